// Round 1
// baseline (1963.033 us; speedup 1.0000x reference)
//
#include <hip/hip_runtime.h>
#include <cmath>

constexpr int T_STEPS = 512;
constexpr int BATCH   = 1024;
constexpr int DIM     = 128;
constexpr int LATENT  = 256;
constexpr int OUT_DIM = 64;

// grid = 256 blocks (1/CU), block = 512 threads = 8 waves.
// Each block owns 4 batch rows. Wave kg (=tid>>6) owns a k-slice of the
// dot products; thread computes a 4(col)x4(row) outer-product tile.
__global__ __launch_bounds__(512, 2)
void rnn_fp32_kernel(const float* __restrict__ x,    // [512][1024][128]
                     const float* __restrict__ h0,   // [1024][256]
                     const float* __restrict__ Wi,   // [128][256]
                     const float* __restrict__ bi,   // [256]
                     const float* __restrict__ Wh,   // [256][256]
                     const float* __restrict__ Wd,   // [256][64]
                     const float* __restrict__ bd,   // [64]
                     float* __restrict__ out)        // [1024][64]
{
    __shared__ float xs[2][DIM][4];       // x[t] staged, [d][row], double-buffered
    __shared__ float hs[2][LATENT][4];    // h, [k][row], double-buffered
    __shared__ float red[8][64][16];      // per-wave partial sums

    const int tid = threadIdx.x;
    const int kg  = tid >> 6;             // wave id = k-group, 0..7
    const int ct  = tid & 63;             // column-thread: cols 4*ct..4*ct+3
    const int b0  = blockIdx.x << 2;      // first batch row of this block
    const int l_r = tid >> 1;             // reduce phase: latent index
    const int r0  = (tid & 1) << 1;       // reduce phase: row pair
    const float bias_l = bi[l_r];

    // stage initial h and x(t=0)
    for (int i = tid; i < 4 * LATENT; i += 512) {
        const int r = i >> 8, k = i & 255;
        hs[0][k][r] = h0[(size_t)(b0 + r) * LATENT + k];
    }
    xs[0][tid & 127][tid >> 7] = x[(size_t)b0 * DIM + tid];

    const float* __restrict__ wi_base = Wi + (ct << 2);
    const float* __restrict__ wh_base = Wh + (ct << 2);

    int cur = 0;
    for (int t = 0; t < T_STEPS; ++t) {
        __syncthreads();   // xs[t&1] and hs[cur] ready

        // prefetch next step's x element (latency hidden under compute)
        const int tn = (t + 1 < T_STEPS) ? (t + 1) : t;
        const float xnext = x[((size_t)tn * BATCH + b0) * DIM + tid];

        float acc[4][4];
        #pragma unroll
        for (int c = 0; c < 4; ++c)
            #pragma unroll
            for (int r = 0; r < 4; ++r) acc[c][r] = 0.f;

        // input-projection slice: d in [kg*16, kg*16+16)
        {
            const int d0 = kg << 4;
            #pragma unroll 4
            for (int dd = 0; dd < 16; ++dd) {
                const int d = d0 + dd;
                const float4 w4 = *reinterpret_cast<const float4*>(wi_base + (size_t)d * LATENT);
                const float4 x4 = *reinterpret_cast<const float4*>(&xs[t & 1][d][0]);
                const float w[4] = {w4.x, w4.y, w4.z, w4.w};
                const float v[4] = {x4.x, x4.y, x4.z, x4.w};
                #pragma unroll
                for (int c = 0; c < 4; ++c)
                    #pragma unroll
                    for (int r = 0; r < 4; ++r) acc[c][r] += w[c] * v[r];
            }
        }
        // recurrent slice: k in [kg*32, kg*32+32)
        {
            const int k0 = kg << 5;
            #pragma unroll 4
            for (int kk = 0; kk < 32; ++kk) {
                const int k = k0 + kk;
                const float4 w4 = *reinterpret_cast<const float4*>(wh_base + (size_t)k * LATENT);
                const float4 h4 = *reinterpret_cast<const float4*>(&hs[cur][k][0]);
                const float w[4] = {w4.x, w4.y, w4.z, w4.w};
                const float v[4] = {h4.x, h4.y, h4.z, h4.w};
                #pragma unroll
                for (int c = 0; c < 4; ++c)
                    #pragma unroll
                    for (int r = 0; r < 4; ++r) acc[c][r] += w[c] * v[r];
            }
        }

        // stage next x into the other buffer (reads of this buffer finished
        // before the previous barrier)
        xs[(t + 1) & 1][tid & 127][tid >> 7] = xnext;

        // write partial sums
        #pragma unroll
        for (int c = 0; c < 4; ++c)
            *reinterpret_cast<float4*>(&red[kg][ct][c << 2]) =
                make_float4(acc[c][0], acc[c][1], acc[c][2], acc[c][3]);

        __syncthreads();   // red ready

        // reduce 8 partials + bias, tanh, write next h (2 outputs/thread)
        {
            float s0 = bias_l, s1 = bias_l;
            #pragma unroll
            for (int g = 0; g < 8; ++g) {
                const float2 v = *reinterpret_cast<const float2*>(
                    &red[g][l_r >> 2][((l_r & 3) << 2) + r0]);
                s0 += v.x; s1 += v.y;
            }
            *reinterpret_cast<float2*>(&hs[cur ^ 1][l_r][r0]) =
                make_float2(tanhf(s0), tanhf(s1));
        }
        cur ^= 1;
    }

    __syncthreads();
    // decode: out = sigmoid(h_final @ Wd + bd), 4 rows x 64 cols per block
    if (tid < 256) {
        const int r = tid >> 6, o = tid & 63;
        float acc = bd[o];
        #pragma unroll 8
        for (int k = 0; k < LATENT; ++k)
            acc += hs[cur][k][r] * Wd[(size_t)k * OUT_DIM + o];
        out[(size_t)(b0 + r) * OUT_DIM + o] = 1.f / (1.f + expf(-acc));
    }
}

extern "C" void kernel_launch(void* const* d_in, const int* in_sizes, int n_in,
                              void* d_out, int out_size, void* d_ws, size_t ws_size,
                              hipStream_t stream) {
    const float* x  = (const float*)d_in[0];
    const float* h0 = (const float*)d_in[1];
    const float* Wi = (const float*)d_in[2];
    const float* bi = (const float*)d_in[3];
    const float* Wh = (const float*)d_in[4];
    const float* Wd = (const float*)d_in[5];
    const float* bd = (const float*)d_in[6];
    float* out = (float*)d_out;

    hipLaunchKernelGGL(rnn_fp32_kernel, dim3(BATCH / 4), dim3(512), 0, stream,
                       x, h0, Wi, bi, Wh, Wd, bd, out);
}